// Round 1
// baseline (134.760 us; speedup 1.0000x reference)
//
#include <hip/hip_runtime.h>

#define TT 8
#define NN 2048
#define SS 8192
#define MM (NN * SS)   // 16777216 elements

// Bernoulli integer thresholds: p * 2^23 (all probabilities are dyadic k/128)
#define TH_CAP10  655360u    // 10/128 * 2^23  (ucapture, uminus)
#define TH_SEARCH 65536u     //  1/128 * 2^23
#define TH_BACK   6291456u   // 96/128 * 2^23
#define TH_MIN    262144u    //  4/128 * 2^23

struct KeyPack { unsigned k[20]; };
// layout: [0:2)=rk0(fplus) [2:4)=rk1(fminus) [4:6)=rk2(ucap) [6:8)=rk3(uminus)
//         [8:10)=rk4(usearch) [10:12)=rk5(ubackoff) [12:14)=rk6(umin1)
//         [14:16)=k7a(umin2) [16:18)=k7b(umin3) [18:20)=k7c(umin4)

__host__ __device__ __forceinline__ void tf2x32(unsigned k0, unsigned k1,
                                                unsigned x0, unsigned x1,
                                                unsigned& o0, unsigned& o1) {
  const unsigned ks2 = k0 ^ k1 ^ 0x1BD11BDAu;
  x0 += k0; x1 += k1;
#define TFR(r) { x0 += x1; x1 = (x1 << (r)) | (x1 >> (32 - (r))); x1 ^= x0; }
  TFR(13) TFR(15) TFR(26) TFR(6)
  x0 += k1;  x1 += ks2 + 1u;
  TFR(17) TFR(29) TFR(16) TFR(24)
  x0 += ks2; x1 += k0 + 2u;
  TFR(13) TFR(15) TFR(26) TFR(6)
  x0 += k0;  x1 += k1 + 3u;
  TFR(17) TFR(29) TFR(16) TFR(24)
  x0 += k1;  x1 += ks2 + 4u;
  TFR(13) TFR(15) TFR(26) TFR(6)
  x0 += ks2; x1 += k0 + 5u;
#undef TFR
  o0 = x0; o1 = x1;
}

__global__ __launch_bounds__(256) void ModSTDP_58823872086838_kernel(
    const int* __restrict__ inS,    // [T, N, S] int32 0/1
    const int* __restrict__ outS,   // [T, N]    int32 0/1
    const float* __restrict__ W,    // [N, S]
    float* __restrict__ out,        // [N, S]
    KeyPack kp)
{
  const unsigned tid  = blockIdx.x * blockDim.x + threadIdx.x;
  const unsigned base = tid << 2;               // 4 elements per thread
  const unsigned n    = base >> 13;             // row (S = 8192 = 2^13)

  // out_t for this row (8 wave-mostly-uniform cached loads)
  int osum = 0;
#pragma unroll
  for (int t = 0; t < TT; ++t) osum += outS[t * NN + n];
  const int  ot   = 8 - osum;
  const bool outF = ot < 8;

  const float4 w4 = *reinterpret_cast<const float4*>(W + base);

  int c0 = 0, c1 = 0, c2 = 0, c3 = 0;
#pragma unroll
  for (int t = 0; t < TT; ++t) {
    const int4 sp = *reinterpret_cast<const int4*>(inS + (size_t)t * MM + base);
    c0 += sp.x; c1 += sp.y; c2 += sp.z; c3 += sp.w;
  }
  const int   cnt[4] = {c0, c1, c2, c3};
  const float wv[4]  = {w4.x, w4.y, w4.z, w4.w};
  float res[4];

#pragma unroll
  for (int e = 0; e < 4; ++e) {
    const unsigned j = base + (unsigned)e;
    const float w = fminf(fmaxf(wv[e], 0.0f), 8.0f);
    const int  it  = 8 - cnt[e];
    const bool inF = it < 8;
    const bool b1 = inF && outF && (it <= ot);
    const bool b2 = inF && outF && (it > ot);
    const bool b3 = inF && !outF;
    const bool b4 = (!inF) && outF;
    const bool active = inF || outF;

    // p_plus / p_minus exactly as XLA (no FMA contraction)
    const float wn = w * 0.125f;
    const float pp = __fmul_rn(wn, __fsub_rn(2.0f, wn));
    const float pm = __fmul_rn(__fsub_rn(1.0f, wn), __fadd_rn(1.0f, wn));

    const bool useP = b1 || b3;                 // needs fplus, else fminus
    const float    pA  = useP ? pp : pm;
    const unsigned ka0 = useP ? kp.k[0] : kp.k[2];
    const unsigned ka1 = useP ? kp.k[1] : kp.k[3];

    const unsigned kb0 = b1 ? kp.k[4]  : (b2 ? kp.k[6]  : (b3 ? kp.k[8]  : kp.k[10]));
    const unsigned kb1 = b1 ? kp.k[5]  : (b2 ? kp.k[7]  : (b3 ? kp.k[9]  : kp.k[11]));
    const unsigned thB = (b1 || b2) ? TH_CAP10 : (b3 ? TH_SEARCH : TH_BACK);
    const unsigned kc0 = b1 ? kp.k[12] : (b2 ? kp.k[14] : (b3 ? kp.k[16] : kp.k[18]));
    const unsigned kc1 = b1 ? kp.k[13] : (b2 ? kp.k[15] : (b3 ? kp.k[17] : kp.k[19]));

    unsigned a0, a1, bb0, bb1, cc0, cc1;
    tf2x32(ka0, ka1, 0u, j, a0, a1);
    const unsigned bitsA = a0 ^ a1;             // partitionable: x0 ^ x1
    const float u = __uint_as_float((bitsA >> 9) | 0x3f800000u) - 1.0f;
    const bool fab = u < pA;                    // fplus or fminus

    tf2x32(kb0, kb1, 0u, j, bb0, bb1);
    const bool gate = (((bb0 ^ bb1) >> 9) < thB);

    tf2x32(kc0, kc1, 0u, j, cc0, cc1);
    const bool um = (((cc0 ^ cc1) >> 9) < TH_MIN);

    const bool doit = active && gate && (fab || um);
    const float sgn = (b2 || b4) ? -1.0f : 1.0f;
    res[e] = doit ? (w + sgn) : w;
  }

  *reinterpret_cast<float4*>(out + base) =
      make_float4(res[0], res[1], res[2], res[3]);
}

extern "C" void kernel_launch(void* const* d_in, const int* in_sizes, int n_in,
                              void* d_out, int out_size, void* d_ws, size_t ws_size,
                              hipStream_t stream) {
  const int*   inS  = (const int*)d_in[0];
  const int*   outS = (const int*)d_in[1];
  const float* W    = (const float*)d_in[2];
  float*       out  = (float*)d_out;

  // Host-side key derivation (pure arithmetic — graph-capture safe).
  // jax.random.key(42) -> (0, 42). Fold-like split (threefry_partitionable):
  // rk[i] = threefry(key, (0, i));  k7{a,b,c} = threefry(rk7, (0, {0,1,2}))
  unsigned rk[16];
  for (unsigned i = 0; i < 8; ++i) {
    unsigned o0, o1;
    tf2x32(0u, 42u, 0u, i, o0, o1);
    rk[2 * i] = o0; rk[2 * i + 1] = o1;
  }
  KeyPack kp;
  for (int i = 0; i < 14; ++i) kp.k[i] = rk[i];      // rk0..rk6
  for (unsigned i = 0; i < 3; ++i) {
    unsigned o0, o1;
    tf2x32(rk[14], rk[15], 0u, i, o0, o1);
    kp.k[14 + 2 * i] = o0; kp.k[15 + 2 * i] = o1;
  }

  const int threads = MM / 4;
  dim3 block(256), grid(threads / 256);
  ModSTDP_58823872086838_kernel<<<grid, block, 0, stream>>>(inS, outS, W, out, kp);
}